// Round 5
// baseline (431.367 us; speedup 1.0000x reference)
//
#include <hip/hip_runtime.h>

// ---------------------------------------------------------------------------
// Attention block: out = SDPA(RoPE(x@wq^T), RoPE(x@wk^T), x@wv^T) @ wo^T
// B=2 S=2048 D=2048 H=16 HD=128, causal, start_pos=0.
// R5: gemms -> BK=64 (half the barrier drains) + XOR-swizzled LDS
//     (conflict-free ds_read_b128). flash -> single barrier per iter
//     (K LDS-dbuf), V^T in a register double-buffer reloaded inside PV
//     (no V LDS traffic, no second drain).
// ---------------------------------------------------------------------------

typedef __bf16 bf16_t;
typedef __bf16 bf16x4 __attribute__((ext_vector_type(4)));
typedef __bf16 bf16x8 __attribute__((ext_vector_type(8)));
typedef float  f32x4  __attribute__((ext_vector_type(4)));

#define DEV __device__ __forceinline__

DEV void async_copy16(const bf16_t* g, bf16_t* lds_uniform_base) {
    __builtin_amdgcn_global_load_lds(
        (const __attribute__((address_space(1))) void*)g,
        (__attribute__((address_space(3))) void*)lds_uniform_base,
        16, 0, 0);
}

// ---------------------------------------------------------------------------
__global__ void cast_all(const float* __restrict__ x,  const float* __restrict__ wq,
                         const float* __restrict__ wk, const float* __restrict__ wv,
                         const float* __restrict__ wo,
                         bf16_t* __restrict__ xb, bf16_t* __restrict__ W3,
                         bf16_t* __restrict__ wob)
{
    const int i = blockIdx.x * blockDim.x + threadIdx.x;
    const float4* src;
    bf16x4* dst;
    if (i < 2097152) {
        src = (const float4*)x + i;
        dst = (bf16x4*)xb + i;
    } else {
        const int j   = i - 2097152;
        const int r   = j >> 20;
        const int off = j & 1048575;
        const float* s4 = (r == 0) ? wq : (r == 1) ? wk : (r == 2) ? wv : wo;
        src = (const float4*)s4 + off;
        dst = (r < 3) ? ((bf16x4*)W3 + (long)r * 1048576 + off)
                      : ((bf16x4*)wob + off);
    }
    const float4 v = *src;
    bf16x4 o = { (bf16_t)v.x, (bf16_t)v.y, (bf16_t)v.z, (bf16_t)v.w };
    *dst = o;
}

// ---------------------------------------------------------------------------
// Fused QKV projection: C = x(4096x2048) * W3(6144x2048)^T. BK=64.
// LDS [128][64], 8-elem chunks, chunk cs of row holds global chunk cs^(row&7)
// -> frag reads conflict-free (8 chunk-groups x 2 lanes = free 2-way).
// n in [0,2048): RoPE -> Q ; [2048,4096): RoPE -> K ; [4096,6144): V^T.
// V^T layout: VT[((b*16+h)*128 + d)*2048 + s]
// ---------------------------------------------------------------------------
__global__ __launch_bounds__(256)
void gemm_qkv(const bf16_t* __restrict__ A, const bf16_t* __restrict__ Bm,
              bf16_t* __restrict__ Qo, bf16_t* __restrict__ Ko,
              bf16_t* __restrict__ VTo,
              const float* __restrict__ cosT, const float* __restrict__ sinT)
{
    constexpr int K = 2048;
    __shared__ bf16_t As[128 * 64];
    __shared__ bf16_t Bs[128 * 64];

    const int tid  = threadIdx.x;
    const int w    = tid >> 6;
    const int lane = tid & 63;
    const int l16  = lane & 15;
    const int quad = lane >> 4;
    const int l7   = l16 & 7;
    const int wm   = w >> 1, wn = w & 1;

    const int id   = blockIdx.x;
    const int xcd  = id & 7;
    const int slot = id >> 3;           // 0..191
    const int nl   = slot % 6;
    const int ml   = slot / 6;
    const long n0  = (long)(xcd * 6 + nl) * 128;
    const long m0  = (long)ml * 128;

    f32x4 acc[4][4] = {};

    // staging: chunk c = i*256+tid -> LDS row c>>3, slot c&7 (holds global
    // chunk (c&7)^(row&7)); dest = tile + i*2048 + w*512 (uniform + lane*16B)
    const bf16_t* Ag[4];
    const bf16_t* Bg[4];
    #pragma unroll
    for (int i = 0; i < 4; ++i) {
        const int c   = i * 256 + tid;
        const int row = c >> 3;
        const int col = ((c & 7) ^ (row & 7)) * 8;
        Ag[i] = A  + (m0 + row) * K + col;
        Bg[i] = Bm + (n0 + row) * K + col;
    }

    for (int k0 = 0; k0 < K; k0 += 64) {
        __syncthreads();
        #pragma unroll
        for (int i = 0; i < 4; ++i) {
            async_copy16(Ag[i] + k0, As + i * 2048 + w * 512);
            async_copy16(Bg[i] + k0, Bs + i * 2048 + w * 512);
        }
        __syncthreads();

        #pragma unroll
        for (int kc = 0; kc < 2; ++kc) {
            bf16x8 af[4], bfr[4];
            #pragma unroll
            for (int t = 0; t < 4; ++t) {
                const int cs = ((kc * 4 + quad) ^ l7) * 8;
                af[t]  = *(const bf16x8*)&As[(wm * 64 + t * 16 + l16) * 64 + cs];
                bfr[t] = *(const bf16x8*)&Bs[(wn * 64 + t * 16 + l16) * 64 + cs];
            }
            #pragma unroll
            for (int mt = 0; mt < 4; ++mt)
                #pragma unroll
                for (int nt = 0; nt < 4; ++nt)
                    acc[mt][nt] = __builtin_amdgcn_mfma_f32_16x16x32_bf16(
                        af[mt], bfr[nt], acc[mt][nt], 0, 0, 0);
        }
    }

    const int region = (int)(n0 >> 11);   // block-uniform: 0=Q, 1=K, 2=V
    #pragma unroll
    for (int mt = 0; mt < 4; ++mt) {
        #pragma unroll
        for (int nt = 0; nt < 4; ++nt) {
            if (region < 2) {
                bf16_t* dst = (region == 0) ? Qo : Ko;
                #pragma unroll
                for (int r = 0; r < 4; ++r) {
                    const long m = m0 + wm * 64 + mt * 16 + quad * 4 + r;
                    const long n = n0 + wn * 64 + nt * 16 + l16;
                    float v = acc[mt][nt][r];
                    const float partner = __shfl_xor(v, 1);
                    const int d    = (int)n & 127;
                    const int fidx = ((int)m & 2047) * 64 + (d >> 1);
                    const float c = cosT[fidx], s = sinT[fidx];
                    v = ((int)n & 1) ? fmaf(partner, s, v * c)
                                     : (v * c - partner * s);
                    dst[m * 2048 + (n & 2047)] = (bf16_t)v;
                }
            } else {
                const long m  = m0 + wm * 64 + mt * 16 + quad * 4;   // r=0 base
                const int  np = (int)(n0 + wn * 64 + nt * 16 + l16) - 4096;
                bf16x4 pk;
                #pragma unroll
                for (int r = 0; r < 4; ++r) pk[r] = (bf16_t)acc[mt][nt][r];
                const int b  = (int)(m >> 11);
                const int s0 = (int)m & 2047;
                const long idx = ((long)(b * 16 + (np >> 7)) * 128 + (np & 127)) * 2048 + s0;
                *(bf16x4*)&VTo[idx] = pk;
            }
        }
    }
}

// ---------------------------------------------------------------------------
// Output projection: C = Ob(4096x2048) * wo(2048x2048)^T -> fp32. BK=64.
// ---------------------------------------------------------------------------
__global__ __launch_bounds__(256)
void gemm_out(const bf16_t* __restrict__ A, const bf16_t* __restrict__ Bm,
              float* __restrict__ Cp)
{
    constexpr int K = 2048, N = 2048;
    __shared__ bf16_t As[128 * 64];
    __shared__ bf16_t Bs[128 * 64];

    const int tid  = threadIdx.x;
    const int w    = tid >> 6;
    const int lane = tid & 63;
    const int l16  = lane & 15;
    const int quad = lane >> 4;
    const int l7   = l16 & 7;
    const int wm   = w >> 1, wn = w & 1;

    const int id   = blockIdx.x;
    const int xcd  = id & 7;
    const int slot = id >> 3;           // 0..63
    const long n0  = (long)(xcd * 2 + (slot & 1)) * 128;
    const long m0  = (long)(slot >> 1) * 128;

    f32x4 acc[4][4] = {};

    const bf16_t* Ag[4];
    const bf16_t* Bg[4];
    #pragma unroll
    for (int i = 0; i < 4; ++i) {
        const int c   = i * 256 + tid;
        const int row = c >> 3;
        const int col = ((c & 7) ^ (row & 7)) * 8;
        Ag[i] = A  + (m0 + row) * K + col;
        Bg[i] = Bm + (n0 + row) * K + col;
    }

    for (int k0 = 0; k0 < K; k0 += 64) {
        __syncthreads();
        #pragma unroll
        for (int i = 0; i < 4; ++i) {
            async_copy16(Ag[i] + k0, As + i * 2048 + w * 512);
            async_copy16(Bg[i] + k0, Bs + i * 2048 + w * 512);
        }
        __syncthreads();

        #pragma unroll
        for (int kc = 0; kc < 2; ++kc) {
            bf16x8 af[4], bfr[4];
            #pragma unroll
            for (int t = 0; t < 4; ++t) {
                const int cs = ((kc * 4 + quad) ^ l7) * 8;
                af[t]  = *(const bf16x8*)&As[(wm * 64 + t * 16 + l16) * 64 + cs];
                bfr[t] = *(const bf16x8*)&Bs[(wn * 64 + t * 16 + l16) * 64 + cs];
            }
            #pragma unroll
            for (int mt = 0; mt < 4; ++mt)
                #pragma unroll
                for (int nt = 0; nt < 4; ++nt)
                    acc[mt][nt] = __builtin_amdgcn_mfma_f32_16x16x32_bf16(
                        af[mt], bfr[nt], acc[mt][nt], 0, 0, 0);
        }
    }

    #pragma unroll
    for (int mt = 0; mt < 4; ++mt)
        #pragma unroll
        for (int nt = 0; nt < 4; ++nt)
            #pragma unroll
            for (int r = 0; r < 4; ++r) {
                const long m = m0 + wm * 64 + mt * 16 + quad * 4 + r;
                const long n = n0 + wn * 64 + nt * 16 + l16;
                Cp[m * N + n] = acc[mt][nt][r];
            }
}

// ---------------------------------------------------------------------------
// Flash attention R5. Grid 1-D 512, 256 thr = 4 waves; Q-tile 128 rows,
// wave owns 32. ONE barrier per iter: K LDS double-buffer (staged a full
// iter ahead; dbuf means the single barrier both guards buffer reuse and
// drains the in-flight tile). V^T never touches LDS: 16 bf16x8 register
// double-buffer, each slot reloaded global->VGPR right after its last PV
// use (wave-identical addresses -> L1/L2 broadcast; drain distance =
// barrier + QK + softmax). Fixed-M softmax (p = exp2(z*SC - 24)).
// id -> (xcd, head, qt) with qt reversed in upper half for causal balance.
// ---------------------------------------------------------------------------
__global__ __launch_bounds__(256, 2)
void flash_attn(const bf16_t* __restrict__ Q, const bf16_t* __restrict__ Kg,
                const bf16_t* __restrict__ VT, bf16_t* __restrict__ O)
{
    constexpr int S = 2048, D = 2048;
    constexpr int PSTR = 72;
    __shared__ bf16_t Kb[2][64 * 128];   // [k_row][d], chunk-swizzled
    __shared__ bf16_t Ps[128 * PSTR];

    const int tid  = threadIdx.x;
    const int w    = tid >> 6, lane = tid & 63, l16 = lane & 15, quad = lane >> 4;
    const int l7   = l16 & 7;

    const int id   = blockIdx.x;
    const int half = id >> 8;            // 0: qt 0..7, 1: qt 15..8
    const int rest = id & 255;
    const int xcd  = rest & 7;
    const int s    = rest >> 3;          // 0..31
    const int hh   = s & 3;
    const int qh   = s >> 2;             // 0..7
    const int qt   = half ? (15 - qh) : qh;
    const int bh   = xcd * 4 + hh;
    const int b    = bh >> 4, h = bh & 15;
    const int q0   = qt * 128;

    // Q fragments (B-operand): n = q (l16), k = d
    bf16x8 qf[2][4];
    {
        const bf16_t* qp = Q + (long)(b * S + q0 + w * 32 + l16) * D + h * 128 + quad * 8;
        #pragma unroll
        for (int qi = 0; qi < 2; ++qi)
            #pragma unroll
            for (int kk = 0; kk < 4; ++kk)
                qf[qi][kk] = *(const bf16x8*)(qp + qi * 16 * D + kk * 32);
    }

    // K staging offsets (XOR chunk swizzle over 16 chunks/row)
    int koff[4];
    #pragma unroll
    for (int i = 0; i < 4; ++i) {
        const int c  = i * 256 + tid;
        const int kr = c >> 4, cs = c & 15;
        const int cc = (cs & 8) | ((cs & 7) ^ (kr & 7));
        koff[i] = kr * D + cc * 8;
    }
    const bf16_t* Kst = Kg + (long)b * S * D + h * 128;
    const bf16_t* Vl  = VT + (long)bh * 128 * S + (long)l16 * S + quad * 8;

    f32x4 oacc[2][8] = {};
    float li[2] = { 0.f, 0.f };
    const float SC = 0.08838834764831845f * 1.44269504088896340f;

    const int nkt = 2 * qt + 2;

    // prologue: stage K[0] into Kb[0]; V[0] fragments into registers
    #pragma unroll
    for (int i = 0; i < 4; ++i)
        async_copy16(Kst + koff[i], &Kb[0][i * 2048 + w * 512]);
    bf16x8 vf[2][8];
    #pragma unroll
    for (int ks = 0; ks < 2; ++ks)
        #pragma unroll
        for (int nv = 0; nv < 8; ++nv)
            vf[ks][nv] = *(const bf16x8*)(Vl + (long)nv * 16 * S + ks * 32);

    for (int kt = 0; kt < nkt; ++kt) {
        __syncthreads();   // Kb[kt&1] + vf landed; Kb[(kt+1)&1] reads done
        const int knx = (kt + 1 < nkt) ? (kt + 1) : kt;   // clamp (stay in ws)
        #pragma unroll
        for (int i = 0; i < 4; ++i)
            async_copy16(Kst + (long)knx * 64 * D + koff[i],
                         &Kb[(kt + 1) & 1][i * 2048 + w * 512]);

        const bool active = (kt * 64 <= q0 + w * 32 + 31);
        if (active) {
            // ---- S^T = K·Q^T ----
            f32x4 sc[4][2] = {};
            const bf16_t* Kcur = Kb[kt & 1];
            #pragma unroll
            for (int kk = 0; kk < 4; ++kk)
                #pragma unroll
                for (int mt = 0; mt < 4; ++mt) {
                    const int cc = kk * 4 + quad;
                    const bf16x8 kf = *(const bf16x8*)
                        &Kcur[(mt * 16 + l16) * 128 + ((cc & 8) | ((cc & 7) ^ l7)) * 8];
                    sc[mt][0] = __builtin_amdgcn_mfma_f32_16x16x32_bf16(
                        kf, qf[0][kk], sc[mt][0], 0, 0, 0);
                    sc[mt][1] = __builtin_amdgcn_mfma_f32_16x16x32_bf16(
                        kf, qf[1][kk], sc[mt][1], 0, 0, 0);
                }

            // ---- fixed-M softmax + packed P writes ----
            #pragma unroll
            for (int qi = 0; qi < 2; ++qi) {
                const int qg = q0 + w * 32 + qi * 16 + l16;
                float rs = 0.f;
                #pragma unroll
                for (int mt = 0; mt < 4; ++mt) {
                    bf16x4 pk;
                    #pragma unroll
                    for (int r = 0; r < 4; ++r) {
                        const int kg = kt * 64 + mt * 16 + quad * 4 + r;
                        const float p = (kg > qg) ? 0.f
                                      : exp2f(sc[mt][qi][r] * SC - 24.0f);
                        rs += p;
                        pk[r] = (bf16_t)p;
                    }
                    *(bf16x4*)&Ps[(w * 32 + qi * 16 + l16) * PSTR + mt * 16 + quad * 4] = pk;
                }
                li[qi] += rs;
            }

            // ---- O += P·V^T ; reload each vf slot right after last use ----
            #pragma unroll
            for (int ks = 0; ks < 2; ++ks) {
                const bf16x8 pf0 = *(const bf16x8*)
                    &Ps[(w * 32 + l16) * PSTR + ks * 32 + quad * 8];
                const bf16x8 pf1 = *(const bf16x8*)
                    &Ps[(w * 32 + 16 + l16) * PSTR + ks * 32 + quad * 8];
                #pragma unroll
                for (int nv = 0; nv < 8; ++nv) {
                    const bf16x8 vcur = vf[ks][nv];
                    vf[ks][nv] = *(const bf16x8*)
                        (Vl + (long)nv * 16 * S + ks * 32 + (long)knx * 64);
                    oacc[0][nv] = __builtin_amdgcn_mfma_f32_16x16x32_bf16(
                        pf0, vcur, oacc[0][nv], 0, 0, 0);
                    oacc[1][nv] = __builtin_amdgcn_mfma_f32_16x16x32_bf16(
                        pf1, vcur, oacc[1][nv], 0, 0, 0);
                }
            }
        }
    }

    // ---- epilogue: reduce li across quads, normalize, store ----
    #pragma unroll
    for (int qi = 0; qi < 2; ++qi) {
        li[qi] += __shfl_xor(li[qi], 16);
        li[qi] += __shfl_xor(li[qi], 32);
        const float inv = 1.0f / li[qi];
        #pragma unroll
        for (int r = 0; r < 4; ++r) {
            const float invr = __shfl(inv, quad * 4 + r);
            const long  row  = (long)(b * S + q0 + w * 32 + qi * 16 + quad * 4 + r);
            #pragma unroll
            for (int nv = 0; nv < 8; ++nv)
                O[row * D + h * 128 + nv * 16 + l16] = (bf16_t)(oacc[qi][nv][r] * invr);
        }
    }
}

// ---------------------------------------------------------------------------
extern "C" void kernel_launch(void* const* d_in, const int* in_sizes, int n_in,
                              void* d_out, int out_size, void* d_ws, size_t ws_size,
                              hipStream_t stream) {
    const float* x  = (const float*)d_in[0];
    const float* wq = (const float*)d_in[1];
    const float* wk = (const float*)d_in[2];
    const float* wv = (const float*)d_in[3];
    const float* wo = (const float*)d_in[4];
    const float* fc = (const float*)d_in[5];
    const float* fs = (const float*)d_in[6];

    char* ws = (char*)d_ws;
    bf16_t* xb  = (bf16_t*)(ws + 0);
    bf16_t* W3  = (bf16_t*)(ws + (16l << 20));
    bf16_t* wob = (bf16_t*)(ws + (40l << 20));
    bf16_t* Qb  = (bf16_t*)(ws + (48l << 20));
    bf16_t* Kb  = (bf16_t*)(ws + (64l << 20));
    bf16_t* VTb = (bf16_t*)(ws + (80l << 20));
    bf16_t* Ob  = xb;   // x dead after QKV projection

    cast_all<<<24576, 256, 0, stream>>>(x, wq, wk, wv, wo, xb, W3, wob);

    gemm_qkv<<<1536, 256, 0, stream>>>(xb, W3, Qb, Kb, VTb, fc, fs);

    flash_attn<<<512, 256, 0, stream>>>(Qb, Kb, VTb, Ob);

    gemm_out<<<512, 256, 0, stream>>>(Ob, wob, (float*)d_out);
}